// Round 1
// baseline (149.932 us; speedup 1.0000x reference)
//
#include <hip/hip_runtime.h>

// Problem constants (reference: B,T,D,O = 16,1024,1024,10; T==D required)
#define BB 16
#define TT 1024
#define DD 1024
#define OO 10

// ---------------------------------------------------------------------------
// K1: scores[b][o][t] = (dot(logits[b,t,:], W[o,:]) + bias[o]) / O
// Stored TRANSPOSED (B,O,T) so the T-softmax is contiguous.
// One wave processes 4 rows t (reuses each LDS W read 4x). Block = 4 waves
// = 16 rows. Grid = (T/16, B). W (40 KB) staged in LDS per block.
// ---------------------------------------------------------------------------
__global__ __launch_bounds__(256) void scores_kernel(
    const float* __restrict__ logits, const float* __restrict__ W,
    const float* __restrict__ bias, float* __restrict__ scoresT)
{
    __shared__ float sW[OO * DD];  // 40 KB
    const int b   = blockIdx.y;
    const int tid = threadIdx.x;
    for (int i = tid; i < OO * DD; i += 256) sW[i] = W[i];
    __syncthreads();

    const int wave = tid >> 6;
    const int lane = tid & 63;
    const int t0   = blockIdx.x * 16 + wave * 4;
    const float* row0 = logits + ((size_t)b * TT + t0) * DD;

    float acc[4][OO];
#pragma unroll
    for (int r = 0; r < 4; ++r)
#pragma unroll
        for (int o = 0; o < OO; ++o) acc[r][o] = 0.f;

#pragma unroll
    for (int it = 0; it < DD / 256; ++it) {
        const int d = (it * 64 + lane) * 4;  // coalesced: wave covers 256 floats
        float4 x[4];
#pragma unroll
        for (int r = 0; r < 4; ++r)
            x[r] = *(const float4*)(row0 + (size_t)r * DD + d);
#pragma unroll
        for (int o = 0; o < OO; ++o) {
            const float4 w = *(const float4*)(sW + o * DD + d);
#pragma unroll
            for (int r = 0; r < 4; ++r)
                acc[r][o] += x[r].x * w.x + x[r].y * w.y + x[r].z * w.z + x[r].w * w.w;
        }
    }

#pragma unroll
    for (int r = 0; r < 4; ++r) {
#pragma unroll
        for (int o = 0; o < OO; ++o) {
            float v = acc[r][o];
#pragma unroll
            for (int off = 32; off > 0; off >>= 1) v += __shfl_down(v, off, 64);
            if (lane == 0)
                scoresT[((size_t)b * OO + o) * TT + (t0 + r)] =
                    (v + bias[o]) * (1.0f / OO);
        }
    }
}

// ---------------------------------------------------------------------------
// K2: in-place softmax along T for each (b,o) column (contiguous, length 1024).
// One block of 256 threads per column; each thread owns 4 contiguous floats.
// ---------------------------------------------------------------------------
__global__ __launch_bounds__(256) void softmax_kernel(float* __restrict__ s)
{
    float* col = s + (size_t)blockIdx.x * TT;
    const int tid  = threadIdx.x;
    const int wave = tid >> 6;
    const int lane = tid & 63;

    float4 v = *(const float4*)(col + tid * 4);

    __shared__ float sm[4];
    __shared__ float ss[4];

    // block max
    float m = fmaxf(fmaxf(v.x, v.y), fmaxf(v.z, v.w));
#pragma unroll
    for (int off = 32; off > 0; off >>= 1) m = fmaxf(m, __shfl_down(m, off, 64));
    if (lane == 0) sm[wave] = m;
    __syncthreads();
    m = fmaxf(fmaxf(sm[0], sm[1]), fmaxf(sm[2], sm[3]));

    // exp + block sum
    float e0 = __expf(v.x - m), e1 = __expf(v.y - m);
    float e2 = __expf(v.z - m), e3 = __expf(v.w - m);
    float sum = e0 + e1 + e2 + e3;
#pragma unroll
    for (int off = 32; off > 0; off >>= 1) sum += __shfl_down(sum, off, 64);
    if (lane == 0) ss[wave] = sum;
    __syncthreads();
    const float inv = 1.0f / (ss[0] + ss[1] + ss[2] + ss[3]);

    float4 r = make_float4(e0 * inv, e1 * inv, e2 * inv, e3 * inv);
    *(float4*)(col + tid * 4) = r;
}

// ---------------------------------------------------------------------------
// K3: out[b][o][t] = sum_i logits[b,t,i] * w_x[b][o][i]
// Same structure as K1 but the LDS matrix is the per-batch w_x (B,O,T layout
// from K2 — index i along T). Writes d_out in reference (B, O*T) layout.
// ---------------------------------------------------------------------------
__global__ __launch_bounds__(256) void pool_kernel(
    const float* __restrict__ logits, const float* __restrict__ wx,
    float* __restrict__ out)
{
    __shared__ float sW[OO * DD];  // 40 KB
    const int b   = blockIdx.y;
    const int tid = threadIdx.x;
    const float* wxb = wx + (size_t)b * OO * TT;
    for (int i = tid; i < OO * DD; i += 256) sW[i] = wxb[i];
    __syncthreads();

    const int wave = tid >> 6;
    const int lane = tid & 63;
    const int t0   = blockIdx.x * 16 + wave * 4;
    const float* row0 = logits + ((size_t)b * TT + t0) * DD;

    float acc[4][OO];
#pragma unroll
    for (int r = 0; r < 4; ++r)
#pragma unroll
        for (int o = 0; o < OO; ++o) acc[r][o] = 0.f;

#pragma unroll
    for (int it = 0; it < DD / 256; ++it) {
        const int d = (it * 64 + lane) * 4;
        float4 x[4];
#pragma unroll
        for (int r = 0; r < 4; ++r)
            x[r] = *(const float4*)(row0 + (size_t)r * DD + d);
#pragma unroll
        for (int o = 0; o < OO; ++o) {
            const float4 w = *(const float4*)(sW + o * DD + d);
#pragma unroll
            for (int r = 0; r < 4; ++r)
                acc[r][o] += x[r].x * w.x + x[r].y * w.y + x[r].z * w.z + x[r].w * w.w;
        }
    }

#pragma unroll
    for (int r = 0; r < 4; ++r) {
#pragma unroll
        for (int o = 0; o < OO; ++o) {
            float v = acc[r][o];
#pragma unroll
            for (int off = 32; off > 0; off >>= 1) v += __shfl_down(v, off, 64);
            if (lane == 0)
                out[((size_t)b * OO + o) * TT + (t0 + r)] = v;
        }
    }
}

extern "C" void kernel_launch(void* const* d_in, const int* in_sizes, int n_in,
                              void* d_out, int out_size, void* d_ws, size_t ws_size,
                              hipStream_t stream)
{
    const float* logits = (const float*)d_in[0];
    // d_in[1] = decision — unused by the forward math
    const float* W    = (const float*)d_in[2];
    const float* bias = (const float*)d_in[3];
    float* out    = (float*)d_out;
    float* scores = (float*)d_ws;  // B*O*T floats = 655 KB (softmax in-place)

    dim3 grid(TT / 16, BB);
    scores_kernel<<<grid, 256, 0, stream>>>(logits, W, bias, scores);
    softmax_kernel<<<BB * OO, 256, 0, stream>>>(scores);
    pool_kernel<<<grid, 256, 0, stream>>>(logits, scores, out);
}